// Round 7
// baseline (616.696 us; speedup 1.0000x reference)
//
#include <hip/hip_runtime.h>
#include <hip/hip_bf16.h>
#include <hip/hip_fp16.h>
#include <math.h>

#define B_ 16
#define IN_DIM_ 4096
#define D_ 100
#define H_ 200
#define L_ 4
#define N_ (B_*IN_DIM_)     // 65536
#define E_ (8*B_*IN_DIM_)   // 524288
#define EPS_ 1e-7f

typedef __attribute__((ext_vector_type(8))) short bf16x8s;  // 8 bf16 (4 VGPRs)
typedef __attribute__((ext_vector_type(4))) float f32x4;

// hn storage: SLICE-MAJOR. hn_s[slice][node][32 cols fp16 = 64B].
// slice s covers cols 32s..32s+31 (cols 100..127 zero pad).
// Each slice region = 64B * 65536 = 4.19 MB ~= one XCD's L2.
__device__ inline size_t hns_off(int slice, int node){ return ((size_t)slice*N_ + node)*64; }

__device__ inline unsigned pack_bf16x2(float a, float b){
  __hip_bfloat16 x = __float2bfloat16(a), y = __float2bfloat16(b);
  unsigned short ux = *(unsigned short*)&x, uy = *(unsigned short*)&y;
  return (unsigned)ux | ((unsigned)uy << 16);
}

// ---------------- dense branch ----------------
__global__ void dense1_kernel(const float* __restrict__ x, const float* __restrict__ h1_w,
                              float* __restrict__ xs1acc) {
  __shared__ float xl[16][64];
  int k0 = blockIdx.y * 64;
  int t = threadIdx.x;
  for (int i = t; i < 16*64; i += 256) {
    int b = i >> 6, kk = i & 63;
    xl[b][kk] = x[b*IN_DIM_ + k0 + kk];
  }
  __syncthreads();
  int c = blockIdx.x*256 + t;
  if (c >= 1000) return;
  float acc[B_];
  #pragma unroll
  for (int b=0;b<B_;b++) acc[b]=0.f;
  #pragma unroll 4
  for (int kk=0; kk<64; kk++) {
    float w = h1_w[(k0+kk)*1000 + c];
    #pragma unroll
    for (int b=0;b<B_;b++) acc[b] += xl[b][kk]*w;
  }
  #pragma unroll
  for (int b=0;b<B_;b++) atomicAdd(&xs1acc[b*1000+c], acc[b]);
}

// applies h1 bias + leaky inline
__global__ void dense2_kernel(const float* __restrict__ xs1acc, const float* __restrict__ h1_b,
                              const float* __restrict__ h2_w, float* __restrict__ xs2acc) {
  int T = blockIdx.x*256+threadIdx.x;
  if (T >= 100*40) return;
  int c = T % 100, kc = T / 100;
  int k0 = kc*25;
  float acc[B_];
  #pragma unroll
  for (int b=0;b<B_;b++) acc[b]=0.f;
  for (int kk=0;kk<25;kk++){
    int k = k0+kk;
    float w = h2_w[k*100 + c];
    float bk = h1_b[k];
    #pragma unroll
    for (int b=0;b<B_;b++){
      float m = xs1acc[b*1000+k] + bk;
      m = (m>0.f)? m : 0.01f*m;
      acc[b] += m*w;
    }
  }
  #pragma unroll
  for (int b=0;b<B_;b++) atomicAdd(&xs2acc[b*100+c], acc[b]);
}

// ---------------- encoder + LN(layer0) fused, wave per node ----------------
// h: [N][112] fp16 rows; hn -> slice-major hn_s
__global__ void enc_ln_kernel(const float* __restrict__ x, const float* __restrict__ enc_w,
                              const float* __restrict__ enc_b, const float* __restrict__ g0,
                              const float* __restrict__ b0,
                              __half* __restrict__ h, char* __restrict__ hn_s) {
  int wid = (blockIdx.x*256 + threadIdx.x) >> 6;
  int lane = threadIdx.x & 63;
  if (wid >= N_) return;
  float xn = x[wid];
  int c0 = 2*lane, c1 = c0+1;
  bool v = c0 < D_;
  float h0=0.f, h1=0.f;
  if (v){ h0 = fmaf(xn, enc_w[c0], enc_b[c0]); h1 = fmaf(xn, enc_w[c1], enc_b[c1]); }
  float s = h0+h1;
  #pragma unroll
  for (int off=32; off; off>>=1) s += __shfl_xor(s, off, 64);
  float mu = s * (1.f/D_);
  float d0 = v? h0-mu : 0.f, d1 = v? h1-mu : 0.f;
  float q = d0*d0 + d1*d1;
  #pragma unroll
  for (int off=32; off; off>>=1) q += __shfl_xor(q, off, 64);
  float rstd = rsqrtf(q*(1.f/D_) + 1e-5f);
  if (c0 < 112) *(__half2*)&h[(size_t)wid*112 + c0] = __floats2half2_rn(h0, h1);
  float n0 = v? fmaxf(fmaf(d0*rstd, g0[c0], b0[c0]), 0.f) : 0.f;
  float n1 = v? fmaxf(fmaf(d1*rstd, g0[c1], b0[c1]), 0.f) : 0.f;
  *(__half2*)(hn_s + hns_off(c0>>5, wid) + (c0&31)*2) = __floats2half2_rn(n0, n1);
}

// ---------------- CSR build ----------------
__global__ void deg_kernel(const int* __restrict__ dst, int* __restrict__ deg) {
  int e = blockIdx.x*256+threadIdx.x;
  if (e < E_) atomicAdd(&deg[dst[e]], 1);
}

__global__ void scan_kernel(const int* __restrict__ deg, int* __restrict__ row_start) {
  __shared__ int sums[1024];
  int t = threadIdx.x;
  int base = t*64;
  int s = 0;
  for (int j=0;j<64;j++) s += deg[base+j];
  sums[t] = s;
  __syncthreads();
  for (int off=1; off<1024; off<<=1){
    int add = (t>=off)? sums[t-off] : 0;
    __syncthreads();
    sums[t] += add;
    __syncthreads();
  }
  int excl = (t==0)? 0 : sums[t-1];
  int run = excl;
  for (int j=0;j<64;j++){ row_start[base+j] = run; run += deg[base+j]; }
  if (t==1023) row_start[N_] = run;
}

__global__ void scatter_kernel(const int* __restrict__ srcs, const int* __restrict__ dst,
                               const int* __restrict__ row_start, int* __restrict__ cnt,
                               int* __restrict__ sorted_src) {
  int e = blockIdx.x*256+threadIdx.x;
  if (e < E_){
    int d = dst[e];
    int p = row_start[d] + atomicAdd(&cnt[d], 1);
    sorted_src[p] = srcs[e];
  }
}

// ---------------- softmax aggregation, slice-major + XCD affinity ----------
// slot = blockIdx&7 -> XCD. slot = slice*2 + half. Each slot gathers ONLY from
// its slice's contiguous 4.19MB region -> fits that XCD's L2.
// 16-lane group per node (2 cols/lane), 4 nodes/wave, 16 nodes/block.
__global__ void agg_kernel(const char* __restrict__ hn_s, const int* __restrict__ row_start,
                           const int* __restrict__ sorted_src, unsigned* __restrict__ u) {
  int idx = blockIdx.x;
  int slot = idx & 7;
  int slice = slot >> 1;
  int sub = slot & 1;
  int nblk = (idx >> 3)*2 + sub;        // 0..4095
  int t = threadIdx.x;
  int wave = t >> 6, lane = t & 63;
  int group = lane >> 4, lpos = lane & 15;
  int node = nblk*16 + wave*4 + group;
  int beg = row_start[node], end = row_start[node+1];
  int deg = end - beg;
  int mdeg = max(deg, __shfl_xor(deg, 16, 64));
  mdeg = max(mdeg, __shfl_xor(mdeg, 32, 64));
  const char* base = hn_s + (size_t)slice*(N_*64) + lpos*4;
  float s0=0.f, ws0=0.f, s1=0.f, ws1=0.f;
  __half2 wa = {}, wb = {};
  if (0 < deg) wa = *(const __half2*)(base + (size_t)sorted_src[beg+0]*64);
  if (1 < deg) wb = *(const __half2*)(base + (size_t)sorted_src[beg+1]*64);
  for (int j=0; j<mdeg; j++){
    __half2 wc = {};
    if (j+2 < deg) wc = *(const __half2*)(base + (size_t)sorted_src[beg+j+2]*64);
    if (j < deg){
      float v0 = __low2float(wa) + EPS_;
      float v1 = __high2float(wa) + EPS_;
      float e0 = __expf(v0), e1 = __expf(v1);
      s0 += e0; ws0 = fmaf(e0, v0, ws0);
      s1 += e1; ws1 = fmaf(e1, v1, ws1);
    }
    wa = wb; wb = wc;
  }
  __half2 own = *(const __half2*)(base + (size_t)node*64);
  float u0 = ((deg>0)? ws0/s0 : 0.f) + __low2float(own);
  float u1 = ((deg>0)? ws1/s1 : 0.f) + __high2float(own);
  int col0 = slice*32 + lpos*2;
  if (col0 >= D_) { u0 = 0.f; u1 = 0.f; }     // zero K-pad (col0 even)
  u[(size_t)node*64 + slice*16 + lpos] = pack_bf16x2(u0, u1);
}

// ---------------- weight prep: transpose+pad+bf16 once ----------------
__global__ void prep_weights(const float* __restrict__ w1, const float* __restrict__ w2,
                             __hip_bfloat16* __restrict__ w1T, __hip_bfloat16* __restrict__ w2T) {
  int idx = blockIdx.x*256 + threadIdx.x;
  if (idx < L_*224*128) {
    int l = idx / (224*128);
    int rem = idx % (224*128);
    int col = rem / 128, k = rem % 128;
    float v = (col < H_ && k < D_) ? w1[(l*D_ + k)*H_ + col] : 0.f;
    w1T[idx] = __float2bfloat16(v);
  }
  if (idx < L_*112*224) {
    int l = idx / (112*224);
    int rem = idx % (112*224);
    int col = rem / 224, k = rem % 224;
    float v = (col < D_ && k < H_) ? w2[(l*H_ + k)*D_ + col] : 0.f;
    w2T[idx] = __float2bfloat16(v);
  }
}

// ---------------- GEMM1: z = relu(bn(u @ w1 + b1)), bf16 MFMA -------------
__global__ __launch_bounds__(256,2) void gemm1_kernel(
    const __hip_bfloat16* __restrict__ u, const __hip_bfloat16* __restrict__ w1T,
    const float* __restrict__ b1, const float* __restrict__ bng, const float* __restrict__ bnb,
    char* __restrict__ z) {
  __shared__ __align__(16) char lds[288*272];   // u: 64 rows + w1T: 224 rows
  char* uL = lds;
  char* wL = lds + 64*272;
  int t = threadIdx.x;
  size_t row0 = (size_t)blockIdx.x * 64;
  const char* ug = (const char*)(u + row0*128);
  #pragma unroll
  for (int c = t; c < 1024; c += 256) {
    int r = c >> 4, sb = (c & 15) << 4;
    *(float4*)(uL + r*272 + sb) = *(const float4*)(ug + (size_t)r*256 + sb);
  }
  const char* wg = (const char*)w1T;
  #pragma unroll
  for (int c = t; c < 3584; c += 256) {
    int r = c >> 4, sb = (c & 15) << 4;
    *(float4*)(wL + r*272 + sb) = *(const float4*)(wg + (size_t)r*256 + sb);
  }
  __syncthreads();
  int wave = t >> 6, lane = t & 63;
  int l15 = lane & 15;
  int kgb = (lane >> 4) << 4;
  int ar = wave*16 + l15;
  f32x4 acc[14];
  #pragma unroll
  for (int n=0;n<14;n++) acc[n] = (f32x4){0.f,0.f,0.f,0.f};
  #pragma unroll
  for (int ks=0; ks<4; ks++) {
    int kb = ks*64 + kgb;
    bf16x8s a = *(const bf16x8s*)(uL + ar*272 + kb);
    #pragma unroll
    for (int n=0;n<14;n++) {
      bf16x8s b = *(const bf16x8s*)(wL + (n*16 + l15)*272 + kb);
      acc[n] = __builtin_amdgcn_mfma_f32_16x16x32_bf16(a, b, acc[n], 0, 0, 0);
    }
  }
  size_t rbase = row0 + wave*16 + ((lane>>4)<<2);
  #pragma unroll
  for (int n=0;n<14;n++) {
    int col = n*16 + l15;
    float bias = (col < H_) ? b1[col] : 0.f;
    float g    = (col < H_) ? bng[col] : 0.f;
    float bb   = (col < H_) ? bnb[col] : 0.f;
    #pragma unroll
    for (int r=0;r<4;r++) {
      float v = fmaxf((acc[n][r] + bias)*g + bb, 0.f);
      if (col >= H_) v = 0.f;
      *(__hip_bfloat16*)(z + (rbase + r)*448 + 2*col) = __float2bfloat16(v);
    }
  }
}

// ---------------- GEMM2 (+LN epilogue, or +pool on last layer) --------------
// h fp16 [N][112]. LAST=0: h += z@w2+b2, hn_s = fp16(relu(LN(h))) slice-major.
// LAST=1: pooled += column sums of h_new (h not stored).
template<int LAST>
__global__ __launch_bounds__(256,2) void gemm2_kernel(
    const char* __restrict__ z, const __hip_bfloat16* __restrict__ w2T,
    const float* __restrict__ b2, __half* __restrict__ h,
    const float* __restrict__ lng, const float* __restrict__ lnb,
    char* __restrict__ hn_s, float* __restrict__ pooled) {
  __shared__ __align__(16) char lds[176*464];   // z: 64 rows + w2T: 112 rows
  char* zL = lds;
  char* wL = lds + 64*464;
  int t = threadIdx.x;
  size_t row0 = (size_t)blockIdx.x * 64;
  const char* zg = z + row0*448;
  for (int c = t; c < 1792; c += 256) {
    int r = c / 28, sb = (c - r*28) << 4;
    *(float4*)(zL + r*464 + sb) = *(const float4*)(zg + (size_t)r*448 + sb);
  }
  const char* wg = (const char*)w2T;
  for (int c = t; c < 3136; c += 256) {
    int r = c / 28, sb = (c - r*28) << 4;
    *(float4*)(wL + r*464 + sb) = *(const float4*)(wg + (size_t)r*448 + sb);
  }
  __syncthreads();
  int wave = t >> 6, lane = t & 63;
  int l15 = lane & 15;
  int kgb = (lane >> 4) << 4;
  int ar = wave*16 + l15;
  f32x4 acc[7];
  #pragma unroll
  for (int n=0;n<7;n++) acc[n] = (f32x4){0.f,0.f,0.f,0.f};
  #pragma unroll
  for (int ks=0; ks<7; ks++) {
    int kb = ks*64 + kgb;
    bf16x8s a = *(const bf16x8s*)(zL + ar*464 + kb);
    #pragma unroll
    for (int n=0;n<7;n++) {
      bf16x8s b = *(const bf16x8s*)(wL + (n*16 + l15)*464 + kb);
      acc[n] = __builtin_amdgcn_mfma_f32_16x16x32_bf16(a, b, acc[n], 0, 0, 0);
    }
  }
  size_t rbase = row0 + wave*16 + ((lane>>4)<<2);

  float x_[7][4];
  float sum[4]  = {0,0,0,0};
  float sum2[4] = {0,0,0,0};
  float psum[7] = {0,0,0,0,0,0,0};
  #pragma unroll
  for (int n=0;n<7;n++) {
    int col = n*16 + l15;
    bool valid = col < D_;
    float bias = valid ? b2[col] : 0.f;
    #pragma unroll
    for (int r=0;r<4;r++) {
      float xv = 0.f;
      if (valid) xv = acc[n][r] + bias + __half2float(h[(rbase + r)*112 + col]);
      x_[n][r] = xv;
      if (LAST) {
        psum[n] += xv;
      } else {
        sum[r] += xv; sum2[r] += xv*xv;
        if (valid) h[(rbase + r)*112 + col] = __float2half(xv);
      }
    }
  }

  if (LAST) {
    #pragma unroll
    for (int n=0;n<7;n++) {
      psum[n] += __shfl_xor(psum[n], 16, 64);
      psum[n] += __shfl_xor(psum[n], 32, 64);
    }
    __syncthreads();
    float* ps = (float*)lds;             // [4][112]
    if (lane < 16) {
      #pragma unroll
      for (int n=0;n<7;n++) ps[wave*112 + n*16 + l15] = psum[n];
    }
    __syncthreads();
    if (t < D_) {
      float v = ps[t] + ps[112+t] + ps[224+t] + ps[336+t];
      int b = (int)(row0 >> 12);        // row0 / 4096
      atomicAdd(&pooled[b*D_ + t], v);
    }
  } else {
    #pragma unroll
    for (int r=0;r<4;r++) {
      float s = sum[r], s2 = sum2[r];
      #pragma unroll
      for (int m=1;m<16;m<<=1) { s += __shfl_xor(s, m, 16); s2 += __shfl_xor(s2, m, 16); }
      sum[r] = s; sum2[r] = s2;
    }
    #pragma unroll
    for (int n=0;n<7;n++) {
      int col = n*16 + l15;
      float g  = (col < D_) ? lng[col] : 0.f;
      float be = (col < D_) ? lnb[col] : 0.f;
      #pragma unroll
      for (int r=0;r<4;r++) {
        float mu = sum[r]*(1.f/D_);
        float var = sum2[r]*(1.f/D_) - mu*mu;
        float rstd = rsqrtf(var + 1e-5f);
        float hv = fmaxf(fmaf((x_[n][r]-mu)*rstd, g, be), 0.f);
        if (col >= D_) hv = 0.f;
        *(__half*)(hn_s + hns_off(col>>5, rbase + r) + (col&31)*2) = __float2half(hv);
      }
    }
    {
      int col = 112 + l15;               // pad cols 112..127 (slice 3)
      __half zh = __float2half(0.f);
      #pragma unroll
      for (int r=0;r<4;r++)
        *(__half*)(hn_s + hns_off(3, rbase + r) + (col&31)*2) = zh;
    }
  }
}

// ---------------- head (dense2 bias+leaky folded in) ----------------
__global__ void final_kernel(const float* __restrict__ xs2acc, const float* __restrict__ h2_b,
                             const float* __restrict__ pooled,
                             const float* __restrict__ dec_w, const float* __restrict__ dec_b,
                             float* __restrict__ out) {
  __shared__ float red[128];
  int t = threadIdx.x;
  for (int b=0;b<B_;b++){
    float v = 0.f;
    if (t < D_) {
      float xs = xs2acc[b*D_+t] + h2_b[t];
      xs = (xs>0.f)? xs : 0.01f*xs;
      v = (0.5f*xs + (0.5f/IN_DIM_)*pooled[b*D_+t]) * dec_w[t];
    }
    red[t] = v;
    __syncthreads();
    for (int off=64; off; off>>=1){
      if (t < off) red[t] += red[t+off];
      __syncthreads();
    }
    if (t==0) out[b] = red[0] + dec_b[0];
    __syncthreads();
  }
}

extern "C" void kernel_launch(void* const* d_in, const int* in_sizes, int n_in,
                              void* d_out, int out_size, void* d_ws, size_t ws_size,
                              hipStream_t stream) {
  const float* x      = (const float*)d_in[0];
  const int*   eidx   = (const int*)d_in[1];
  const float* enc_w  = (const float*)d_in[3];
  const float* enc_b  = (const float*)d_in[4];
  const float* h1_w   = (const float*)d_in[5];
  const float* h1_b   = (const float*)d_in[6];
  const float* h2_w   = (const float*)d_in[7];
  const float* h2_b   = (const float*)d_in[8];
  const float* ln_g   = (const float*)d_in[9];
  const float* ln_b   = (const float*)d_in[10];
  const float* w1     = (const float*)d_in[11];
  const float* b1     = (const float*)d_in[12];
  const float* bn_g   = (const float*)d_in[13];
  const float* bn_b   = (const float*)d_in[14];
  const float* w2     = (const float*)d_in[15];
  const float* b2     = (const float*)d_in[16];
  const float* dec_w  = (const float*)d_in[17];
  const float* dec_b  = (const float*)d_in[18];
  float* out = (float*)d_out;

  char* ws = (char*)d_ws;
  size_t off = 0;
  auto alloc = [&](size_t bytes)->char* {
    char* p = ws + off;
    off += (bytes + 255) & ~(size_t)255;
    return p;
  };
  __half* h     = (__half*)alloc((size_t)N_*112*2);          // 14.7 MB
  char*  hn_s   = alloc((size_t)N_*256);                     // 16.8 MB (4 slices x [N][64B])
  char*  z      = alloc((size_t)N_*448);                     // 29.4 MB ([N][224] bf16)
  unsigned* u   = (unsigned*)alloc((size_t)N_*64*4);         // 16.8 MB ([N][128] bf16)
  __hip_bfloat16* w1T = (__hip_bfloat16*)alloc((size_t)L_*224*128*2);
  __hip_bfloat16* w2T = (__hip_bfloat16*)alloc((size_t)L_*112*224*2);
  float* xs1    = (float*)alloc(16*1000*4);
  float* xs2    = (float*)alloc(16*100*4);
  float* pooled = (float*)alloc(16*100*4);
  int* deg        = (int*)alloc(N_*4);
  int* row_start  = (int*)alloc((N_+1)*4);
  int* cnt        = (int*)alloc(N_*4);
  int* sorted_src = (int*)alloc(E_*4);

  const int* srcs = eidx;
  const int* dsts = eidx + E_;

  hipMemsetAsync(xs1, 0, 16*1000*4, stream);
  hipMemsetAsync(xs2, 0, 16*100*4, stream);
  hipMemsetAsync(pooled, 0, 16*100*4, stream);
  hipMemsetAsync(deg, 0, N_*4, stream);
  hipMemsetAsync(cnt, 0, N_*4, stream);

  {
    dim3 g1(4, 64);
    dense1_kernel<<<g1, 256, 0, stream>>>(x, h1_w, xs1);
  }
  dense2_kernel<<<16, 256, 0, stream>>>(xs1, h1_b, h2_w, xs2);

  enc_ln_kernel<<<N_/4, 256, 0, stream>>>(x, enc_w, enc_b, ln_g, ln_b, h, hn_s);

  deg_kernel<<<E_/256, 256, 0, stream>>>(dsts, deg);
  scan_kernel<<<1, 1024, 0, stream>>>(deg, row_start);
  scatter_kernel<<<E_/256, 256, 0, stream>>>(srcs, dsts, row_start, cnt, sorted_src);

  prep_weights<<<(L_*224*128+255)/256, 256, 0, stream>>>(w1, w2, w1T, w2T);

  for (int i=0;i<L_;i++){
    agg_kernel<<<(N_/16)*4, 256, 0, stream>>>(hn_s, row_start, sorted_src, u);
    gemm1_kernel<<<N_/64, 256, 0, stream>>>((const __hip_bfloat16*)u,
                                            w1T + (size_t)i*224*128, b1 + i*H_,
                                            bn_g + i*H_, bn_b + i*H_, z);
    if (i < L_-1) {
      gemm2_kernel<0><<<N_/64, 256, 0, stream>>>(z, w2T + (size_t)i*112*224, b2 + i*D_,
                                                 h, ln_g + (i+1)*D_, ln_b + (i+1)*D_,
                                                 hn_s, pooled);
    } else {
      gemm2_kernel<1><<<N_/64, 256, 0, stream>>>(z, w2T + (size_t)i*112*224, b2 + i*D_,
                                                 h, nullptr, nullptr, hn_s, pooled);
    }
  }

  final_kernel<<<1, 128, 0, stream>>>(xs2, h2_b, pooled, dec_w, dec_b, out);
}

// Round 8
// 521.419 us; speedup vs baseline: 1.1827x; 1.1827x over previous
//
#include <hip/hip_runtime.h>
#include <hip/hip_bf16.h>
#include <hip/hip_fp16.h>
#include <math.h>

#define B_ 16
#define IN_DIM_ 4096
#define D_ 100
#define H_ 200
#define L_ 4
#define N_ (B_*IN_DIM_)     // 65536
#define E_ (8*B_*IN_DIM_)   // 524288
#define EPS_ 1e-7f

typedef __attribute__((ext_vector_type(8))) short bf16x8s;  // 8 bf16 (4 VGPRs)
typedef __attribute__((ext_vector_type(4))) float f32x4;

__device__ inline unsigned pack_bf16x2(float a, float b){
  __hip_bfloat16 x = __float2bfloat16(a), y = __float2bfloat16(b);
  unsigned short ux = *(unsigned short*)&x, uy = *(unsigned short*)&y;
  return (unsigned)ux | ((unsigned)uy << 16);
}

// ---------------- dense branch ----------------
__global__ void dense1_kernel(const float* __restrict__ x, const float* __restrict__ h1_w,
                              float* __restrict__ xs1acc) {
  __shared__ float xl[16][64];
  int k0 = blockIdx.y * 64;
  int t = threadIdx.x;
  for (int i = t; i < 16*64; i += 256) {
    int b = i >> 6, kk = i & 63;
    xl[b][kk] = x[b*IN_DIM_ + k0 + kk];
  }
  __syncthreads();
  int c = blockIdx.x*256 + t;
  if (c >= 1000) return;
  float acc[B_];
  #pragma unroll
  for (int b=0;b<B_;b++) acc[b]=0.f;
  #pragma unroll 4
  for (int kk=0; kk<64; kk++) {
    float w = h1_w[(k0+kk)*1000 + c];
    #pragma unroll
    for (int b=0;b<B_;b++) acc[b] += xl[b][kk]*w;
  }
  #pragma unroll
  for (int b=0;b<B_;b++) atomicAdd(&xs1acc[b*1000+c], acc[b]);
}

// applies h1 bias + leaky inline
__global__ void dense2_kernel(const float* __restrict__ xs1acc, const float* __restrict__ h1_b,
                              const float* __restrict__ h2_w, float* __restrict__ xs2acc) {
  int T = blockIdx.x*256+threadIdx.x;
  if (T >= 100*40) return;
  int c = T % 100, kc = T / 100;
  int k0 = kc*25;
  float acc[B_];
  #pragma unroll
  for (int b=0;b<B_;b++) acc[b]=0.f;
  for (int kk=0;kk<25;kk++){
    int k = k0+kk;
    float w = h2_w[k*100 + c];
    float bk = h1_b[k];
    #pragma unroll
    for (int b=0;b<B_;b++){
      float m = xs1acc[b*1000+k] + bk;
      m = (m>0.f)? m : 0.01f*m;
      acc[b] += m*w;
    }
  }
  #pragma unroll
  for (int b=0;b<B_;b++) atomicAdd(&xs2acc[b*100+c], acc[b]);
}

// ---------------- encoder + LN(layer0) fused, wave per node ----------------
// hnb: [N][128] fp16, 256B rows (cols 100..127 zero); h: [N][112] fp16 rows
__global__ void enc_ln_kernel(const float* __restrict__ x, const float* __restrict__ enc_w,
                              const float* __restrict__ enc_b, const float* __restrict__ g0,
                              const float* __restrict__ b0,
                              __half* __restrict__ h, char* __restrict__ hnb) {
  int wid = (blockIdx.x*256 + threadIdx.x) >> 6;
  int lane = threadIdx.x & 63;
  if (wid >= N_) return;
  float xn = x[wid];
  int c0 = 2*lane, c1 = c0+1;
  bool v = c0 < D_;
  float h0=0.f, h1=0.f;
  if (v){ h0 = fmaf(xn, enc_w[c0], enc_b[c0]); h1 = fmaf(xn, enc_w[c1], enc_b[c1]); }
  float s = h0+h1;
  #pragma unroll
  for (int off=32; off; off>>=1) s += __shfl_xor(s, off, 64);
  float mu = s * (1.f/D_);
  float d0 = v? h0-mu : 0.f, d1 = v? h1-mu : 0.f;
  float q = d0*d0 + d1*d1;
  #pragma unroll
  for (int off=32; off; off>>=1) q += __shfl_xor(q, off, 64);
  float rstd = rsqrtf(q*(1.f/D_) + 1e-5f);
  if (c0 < 112) *(__half2*)&h[(size_t)wid*112 + c0] = __floats2half2_rn(h0, h1);
  float n0 = v? fmaxf(fmaf(d0*rstd, g0[c0], b0[c0]), 0.f) : 0.f;
  float n1 = v? fmaxf(fmaf(d1*rstd, g0[c1], b0[c1]), 0.f) : 0.f;
  *(__half2*)(hnb + (size_t)wid*256 + 4*lane) = __floats2half2_rn(n0, n1);
}

// ---------------- CSR build ----------------
__global__ void deg_kernel(const int* __restrict__ dst, int* __restrict__ deg) {
  int e = blockIdx.x*256+threadIdx.x;
  if (e < E_) atomicAdd(&deg[dst[e]], 1);
}

__global__ void scan_kernel(const int* __restrict__ deg, int* __restrict__ row_start) {
  __shared__ int sums[1024];
  int t = threadIdx.x;
  int base = t*64;
  int s = 0;
  for (int j=0;j<64;j++) s += deg[base+j];
  sums[t] = s;
  __syncthreads();
  for (int off=1; off<1024; off<<=1){
    int add = (t>=off)? sums[t-off] : 0;
    __syncthreads();
    sums[t] += add;
    __syncthreads();
  }
  int excl = (t==0)? 0 : sums[t-1];
  int run = excl;
  for (int j=0;j<64;j++){ row_start[base+j] = run; run += deg[base+j]; }
  if (t==1023) row_start[N_] = run;
}

__global__ void scatter_kernel(const int* __restrict__ srcs, const int* __restrict__ dst,
                               const int* __restrict__ row_start, int* __restrict__ cnt,
                               int* __restrict__ sorted_src) {
  int e = blockIdx.x*256+threadIdx.x;
  if (e < E_){
    int d = dst[e];
    int p = row_start[d] + atomicAdd(&cnt[d], 1);
    sorted_src[p] = srcs[e];
  }
}

// ---------------- softmax aggregation, wave per node, depth-4 pipeline ------
__global__ void agg_kernel(const char* __restrict__ hnb, const int* __restrict__ row_start,
                           const int* __restrict__ sorted_src, unsigned* __restrict__ u) {
  int wid = (blockIdx.x*256 + threadIdx.x) >> 6;
  int lane = threadIdx.x & 63;
  if (wid >= N_) return;
  int beg = row_start[wid], end = row_start[wid+1];
  int deg = end - beg;
  const char* lanep = hnb + 4*lane;
  float s0=0.f, ws0=0.f, s1=0.f, ws1=0.f;
  __half2 b0v={}, b1v={}, b2v={}, b3v={};
  if (0 < deg) b0v = *(const __half2*)(lanep + (size_t)sorted_src[beg+0]*256);
  if (1 < deg) b1v = *(const __half2*)(lanep + (size_t)sorted_src[beg+1]*256);
  if (2 < deg) b2v = *(const __half2*)(lanep + (size_t)sorted_src[beg+2]*256);
  if (3 < deg) b3v = *(const __half2*)(lanep + (size_t)sorted_src[beg+3]*256);
  for (int base=0; base<deg; base+=4){
    // issue next chunk's loads before consuming current (4-8 in flight)
    __half2 n0={}, n1={}, n2={}, n3={};
    int nx = base+4;
    if (nx+0 < deg) n0 = *(const __half2*)(lanep + (size_t)sorted_src[beg+nx+0]*256);
    if (nx+1 < deg) n1 = *(const __half2*)(lanep + (size_t)sorted_src[beg+nx+1]*256);
    if (nx+2 < deg) n2 = *(const __half2*)(lanep + (size_t)sorted_src[beg+nx+2]*256);
    if (nx+3 < deg) n3 = *(const __half2*)(lanep + (size_t)sorted_src[beg+nx+3]*256);
    // consume (guards are wave-uniform: deg identical across the wave)
    {
      float v0 = __low2float(b0v)+EPS_, v1 = __high2float(b0v)+EPS_;
      float e0 = __expf(v0), e1 = __expf(v1);
      s0 += e0; ws0 = fmaf(e0, v0, ws0);
      s1 += e1; ws1 = fmaf(e1, v1, ws1);
    }
    if (base+1 < deg){
      float v0 = __low2float(b1v)+EPS_, v1 = __high2float(b1v)+EPS_;
      float e0 = __expf(v0), e1 = __expf(v1);
      s0 += e0; ws0 = fmaf(e0, v0, ws0);
      s1 += e1; ws1 = fmaf(e1, v1, ws1);
    }
    if (base+2 < deg){
      float v0 = __low2float(b2v)+EPS_, v1 = __high2float(b2v)+EPS_;
      float e0 = __expf(v0), e1 = __expf(v1);
      s0 += e0; ws0 = fmaf(e0, v0, ws0);
      s1 += e1; ws1 = fmaf(e1, v1, ws1);
    }
    if (base+3 < deg){
      float v0 = __low2float(b3v)+EPS_, v1 = __high2float(b3v)+EPS_;
      float e0 = __expf(v0), e1 = __expf(v1);
      s0 += e0; ws0 = fmaf(e0, v0, ws0);
      s1 += e1; ws1 = fmaf(e1, v1, ws1);
    }
    b0v=n0; b1v=n1; b2v=n2; b3v=n3;
  }
  __half2 own = *(const __half2*)(lanep + (size_t)wid*256);
  float u0 = ((deg>0)? ws0/s0 : 0.f) + __low2float(own);
  float u1 = ((deg>0)? ws1/s1 : 0.f) + __high2float(own);
  if (lane >= 50) { u0 = 0.f; u1 = 0.f; }     // zero K-pad cols 100..127
  u[(size_t)wid*64 + lane] = pack_bf16x2(u0, u1);
}

// ---------------- weight prep: transpose+pad+bf16 once ----------------
__global__ void prep_weights(const float* __restrict__ w1, const float* __restrict__ w2,
                             __hip_bfloat16* __restrict__ w1T, __hip_bfloat16* __restrict__ w2T) {
  int idx = blockIdx.x*256 + threadIdx.x;
  if (idx < L_*224*128) {
    int l = idx / (224*128);
    int rem = idx % (224*128);
    int col = rem / 128, k = rem % 128;
    float v = (col < H_ && k < D_) ? w1[(l*D_ + k)*H_ + col] : 0.f;
    w1T[idx] = __float2bfloat16(v);
  }
  if (idx < L_*112*224) {
    int l = idx / (112*224);
    int rem = idx % (112*224);
    int col = rem / 224, k = rem % 224;
    float v = (col < D_ && k < H_) ? w2[(l*H_ + k)*D_ + col] : 0.f;
    w2T[idx] = __float2bfloat16(v);
  }
}

// ---------------- GEMM1: z = relu(bn(u @ w1 + b1)), bf16 MFMA -------------
__global__ __launch_bounds__(256,2) void gemm1_kernel(
    const __hip_bfloat16* __restrict__ u, const __hip_bfloat16* __restrict__ w1T,
    const float* __restrict__ b1, const float* __restrict__ bng, const float* __restrict__ bnb,
    char* __restrict__ z) {
  __shared__ __align__(16) char lds[288*272];   // u: 64 rows + w1T: 224 rows
  char* uL = lds;
  char* wL = lds + 64*272;
  int t = threadIdx.x;
  size_t row0 = (size_t)blockIdx.x * 64;
  const char* ug = (const char*)(u + row0*128);
  #pragma unroll
  for (int c = t; c < 1024; c += 256) {
    int r = c >> 4, sb = (c & 15) << 4;
    *(float4*)(uL + r*272 + sb) = *(const float4*)(ug + (size_t)r*256 + sb);
  }
  const char* wg = (const char*)w1T;
  #pragma unroll
  for (int c = t; c < 3584; c += 256) {
    int r = c >> 4, sb = (c & 15) << 4;
    *(float4*)(wL + r*272 + sb) = *(const float4*)(wg + (size_t)r*256 + sb);
  }
  __syncthreads();
  int wave = t >> 6, lane = t & 63;
  int l15 = lane & 15;
  int kgb = (lane >> 4) << 4;
  int ar = wave*16 + l15;
  f32x4 acc[14];
  #pragma unroll
  for (int n=0;n<14;n++) acc[n] = (f32x4){0.f,0.f,0.f,0.f};
  #pragma unroll
  for (int ks=0; ks<4; ks++) {
    int kb = ks*64 + kgb;
    bf16x8s a = *(const bf16x8s*)(uL + ar*272 + kb);
    #pragma unroll
    for (int n=0;n<14;n++) {
      bf16x8s b = *(const bf16x8s*)(wL + (n*16 + l15)*272 + kb);
      acc[n] = __builtin_amdgcn_mfma_f32_16x16x32_bf16(a, b, acc[n], 0, 0, 0);
    }
  }
  size_t rbase = row0 + wave*16 + ((lane>>4)<<2);
  #pragma unroll
  for (int n=0;n<14;n++) {
    int col = n*16 + l15;
    float bias = (col < H_) ? b1[col] : 0.f;
    float g    = (col < H_) ? bng[col] : 0.f;
    float bb   = (col < H_) ? bnb[col] : 0.f;
    #pragma unroll
    for (int r=0;r<4;r++) {
      float v = fmaxf((acc[n][r] + bias)*g + bb, 0.f);
      if (col >= H_) v = 0.f;
      *(__hip_bfloat16*)(z + (rbase + r)*448 + 2*col) = __float2bfloat16(v);
    }
  }
}

// ---------------- GEMM2 (+LN epilogue, or +pool on last layer) --------------
// h fp16 [N][112]. LAST=0: h += z@w2+b2, hnb = fp16(relu(LN(h))).
// LAST=1: pooled += column sums of h_new (h not stored).
template<int LAST>
__global__ __launch_bounds__(256,2) void gemm2_kernel(
    const char* __restrict__ z, const __hip_bfloat16* __restrict__ w2T,
    const float* __restrict__ b2, __half* __restrict__ h,
    const float* __restrict__ lng, const float* __restrict__ lnb,
    char* __restrict__ hnb, float* __restrict__ pooled) {
  __shared__ __align__(16) char lds[176*464];   // z: 64 rows + w2T: 112 rows
  char* zL = lds;
  char* wL = lds + 64*464;
  int t = threadIdx.x;
  size_t row0 = (size_t)blockIdx.x * 64;
  const char* zg = z + row0*448;
  for (int c = t; c < 1792; c += 256) {
    int r = c / 28, sb = (c - r*28) << 4;
    *(float4*)(zL + r*464 + sb) = *(const float4*)(zg + (size_t)r*448 + sb);
  }
  const char* wg = (const char*)w2T;
  for (int c = t; c < 3136; c += 256) {
    int r = c / 28, sb = (c - r*28) << 4;
    *(float4*)(wL + r*464 + sb) = *(const float4*)(wg + (size_t)r*448 + sb);
  }
  __syncthreads();
  int wave = t >> 6, lane = t & 63;
  int l15 = lane & 15;
  int kgb = (lane >> 4) << 4;
  int ar = wave*16 + l15;
  f32x4 acc[7];
  #pragma unroll
  for (int n=0;n<7;n++) acc[n] = (f32x4){0.f,0.f,0.f,0.f};
  #pragma unroll
  for (int ks=0; ks<7; ks++) {
    int kb = ks*64 + kgb;
    bf16x8s a = *(const bf16x8s*)(zL + ar*464 + kb);
    #pragma unroll
    for (int n=0;n<7;n++) {
      bf16x8s b = *(const bf16x8s*)(wL + (n*16 + l15)*464 + kb);
      acc[n] = __builtin_amdgcn_mfma_f32_16x16x32_bf16(a, b, acc[n], 0, 0, 0);
    }
  }
  size_t rbase = row0 + wave*16 + ((lane>>4)<<2);

  float x_[7][4];
  float sum[4]  = {0,0,0,0};
  float sum2[4] = {0,0,0,0};
  float psum[7] = {0,0,0,0,0,0,0};
  #pragma unroll
  for (int n=0;n<7;n++) {
    int col = n*16 + l15;
    bool valid = col < D_;
    float bias = valid ? b2[col] : 0.f;
    #pragma unroll
    for (int r=0;r<4;r++) {
      float xv = 0.f;
      if (valid) xv = acc[n][r] + bias + __half2float(h[(rbase + r)*112 + col]);
      x_[n][r] = xv;
      if (LAST) {
        psum[n] += xv;
      } else {
        sum[r] += xv; sum2[r] += xv*xv;
        if (valid) h[(rbase + r)*112 + col] = __float2half(xv);
      }
    }
  }

  if (LAST) {
    #pragma unroll
    for (int n=0;n<7;n++) {
      psum[n] += __shfl_xor(psum[n], 16, 64);
      psum[n] += __shfl_xor(psum[n], 32, 64);
    }
    __syncthreads();
    float* ps = (float*)lds;             // [4][112]
    if (lane < 16) {
      #pragma unroll
      for (int n=0;n<7;n++) ps[wave*112 + n*16 + l15] = psum[n];
    }
    __syncthreads();
    if (t < D_) {
      float v = ps[t] + ps[112+t] + ps[224+t] + ps[336+t];
      int b = (int)(row0 >> 12);        // row0 / 4096
      atomicAdd(&pooled[b*D_ + t], v);
    }
  } else {
    #pragma unroll
    for (int r=0;r<4;r++) {
      float s = sum[r], s2 = sum2[r];
      #pragma unroll
      for (int m=1;m<16;m<<=1) { s += __shfl_xor(s, m, 16); s2 += __shfl_xor(s2, m, 16); }
      sum[r] = s; sum2[r] = s2;
    }
    #pragma unroll
    for (int n=0;n<7;n++) {
      int col = n*16 + l15;
      float g  = (col < D_) ? lng[col] : 0.f;
      float be = (col < D_) ? lnb[col] : 0.f;
      #pragma unroll
      for (int r=0;r<4;r++) {
        float mu = sum[r]*(1.f/D_);
        float var = sum2[r]*(1.f/D_) - mu*mu;
        float rstd = rsqrtf(var + 1e-5f);
        float hv = fmaxf(fmaf((x_[n][r]-mu)*rstd, g, be), 0.f);
        if (col >= D_) hv = 0.f;
        *(__half*)(hnb + (rbase + r)*256 + 2*col) = __float2half(hv);
      }
    }
    {
      int col = 112 + l15;
      __half zh = __float2half(0.f);
      #pragma unroll
      for (int r=0;r<4;r++)
        *(__half*)(hnb + (rbase + r)*256 + 2*col) = zh;
    }
  }
}

// ---------------- head (dense2 bias+leaky folded in) ----------------
__global__ void final_kernel(const float* __restrict__ xs2acc, const float* __restrict__ h2_b,
                             const float* __restrict__ pooled,
                             const float* __restrict__ dec_w, const float* __restrict__ dec_b,
                             float* __restrict__ out) {
  __shared__ float red[128];
  int t = threadIdx.x;
  for (int b=0;b<B_;b++){
    float v = 0.f;
    if (t < D_) {
      float xs = xs2acc[b*D_+t] + h2_b[t];
      xs = (xs>0.f)? xs : 0.01f*xs;
      v = (0.5f*xs + (0.5f/IN_DIM_)*pooled[b*D_+t]) * dec_w[t];
    }
    red[t] = v;
    __syncthreads();
    for (int off=64; off; off>>=1){
      if (t < off) red[t] += red[t+off];
      __syncthreads();
    }
    if (t==0) out[b] = red[0] + dec_b[0];
    __syncthreads();
  }
}

extern "C" void kernel_launch(void* const* d_in, const int* in_sizes, int n_in,
                              void* d_out, int out_size, void* d_ws, size_t ws_size,
                              hipStream_t stream) {
  const float* x      = (const float*)d_in[0];
  const int*   eidx   = (const int*)d_in[1];
  const float* enc_w  = (const float*)d_in[3];
  const float* enc_b  = (const float*)d_in[4];
  const float* h1_w   = (const float*)d_in[5];
  const float* h1_b   = (const float*)d_in[6];
  const float* h2_w   = (const float*)d_in[7];
  const float* h2_b   = (const float*)d_in[8];
  const float* ln_g   = (const float*)d_in[9];
  const float* ln_b   = (const float*)d_in[10];
  const float* w1     = (const float*)d_in[11];
  const float* b1     = (const float*)d_in[12];
  const float* bn_g   = (const float*)d_in[13];
  const float* bn_b   = (const float*)d_in[14];
  const float* w2     = (const float*)d_in[15];
  const float* b2     = (const float*)d_in[16];
  const float* dec_w  = (const float*)d_in[17];
  const float* dec_b  = (const float*)d_in[18];
  float* out = (float*)d_out;

  char* ws = (char*)d_ws;
  size_t off = 0;
  auto alloc = [&](size_t bytes)->char* {
    char* p = ws + off;
    off += (bytes + 255) & ~(size_t)255;
    return p;
  };
  __half* h     = (__half*)alloc((size_t)N_*112*2);          // 14.7 MB
  char*  hnb    = alloc((size_t)N_*256);                     // 16.8 MB ([N][128] fp16)
  char*  z      = alloc((size_t)N_*448);                     // 29.4 MB ([N][224] bf16)
  unsigned* u   = (unsigned*)alloc((size_t)N_*64*4);         // 16.8 MB ([N][128] bf16)
  __hip_bfloat16* w1T = (__hip_bfloat16*)alloc((size_t)L_*224*128*2);
  __hip_bfloat16* w2T = (__hip_bfloat16*)alloc((size_t)L_*112*224*2);
  float* xs1    = (float*)alloc(16*1000*4);
  float* xs2    = (float*)alloc(16*100*4);
  float* pooled = (float*)alloc(16*100*4);
  int* deg        = (int*)alloc(N_*4);
  int* row_start  = (int*)alloc((N_+1)*4);
  int* cnt        = (int*)alloc(N_*4);
  int* sorted_src = (int*)alloc(E_*4);

  const int* srcs = eidx;
  const int* dsts = eidx + E_;

  hipMemsetAsync(xs1, 0, 16*1000*4, stream);
  hipMemsetAsync(xs2, 0, 16*100*4, stream);
  hipMemsetAsync(pooled, 0, 16*100*4, stream);
  hipMemsetAsync(deg, 0, N_*4, stream);
  hipMemsetAsync(cnt, 0, N_*4, stream);

  {
    dim3 g1(4, 64);
    dense1_kernel<<<g1, 256, 0, stream>>>(x, h1_w, xs1);
  }
  dense2_kernel<<<16, 256, 0, stream>>>(xs1, h1_b, h2_w, xs2);

  enc_ln_kernel<<<N_/4, 256, 0, stream>>>(x, enc_w, enc_b, ln_g, ln_b, h, hnb);

  deg_kernel<<<E_/256, 256, 0, stream>>>(dsts, deg);
  scan_kernel<<<1, 1024, 0, stream>>>(deg, row_start);
  scatter_kernel<<<E_/256, 256, 0, stream>>>(srcs, dsts, row_start, cnt, sorted_src);

  prep_weights<<<(L_*224*128+255)/256, 256, 0, stream>>>(w1, w2, w1T, w2T);

  for (int i=0;i<L_;i++){
    agg_kernel<<<N_/4, 256, 0, stream>>>(hnb, row_start, sorted_src, u);
    gemm1_kernel<<<N_/64, 256, 0, stream>>>((const __hip_bfloat16*)u,
                                            w1T + (size_t)i*224*128, b1 + i*H_,
                                            bn_g + i*H_, bn_b + i*H_, z);
    if (i < L_-1) {
      gemm2_kernel<0><<<N_/64, 256, 0, stream>>>(z, w2T + (size_t)i*112*224, b2 + i*D_,
                                                 h, ln_g + (i+1)*D_, ln_b + (i+1)*D_,
                                                 hnb, pooled);
    } else {
      gemm2_kernel<1><<<N_/64, 256, 0, stream>>>(z, w2T + (size_t)i*112*224, b2 + i*D_,
                                                 h, nullptr, nullptr, hnb, pooled);
    }
  }

  final_kernel<<<1, 128, 0, stream>>>(xs2, h2_b, pooled, dec_w, dec_b, out);
}

// Round 9
// 460.721 us; speedup vs baseline: 1.3385x; 1.1317x over previous
//
#include <hip/hip_runtime.h>
#include <hip/hip_bf16.h>
#include <hip/hip_fp16.h>
#include <math.h>

#define B_ 16
#define IN_DIM_ 4096
#define D_ 100
#define H_ 200
#define L_ 4
#define N_ (B_*IN_DIM_)     // 65536
#define E_ (8*B_*IN_DIM_)   // 524288
#define EPS_ 1e-7f

typedef __attribute__((ext_vector_type(8))) short bf16x8s;  // 8 bf16 (4 VGPRs)
typedef __attribute__((ext_vector_type(4))) float f32x4;

__device__ inline unsigned pack_bf16x2(float a, float b){
  __hip_bfloat16 x = __float2bfloat16(a), y = __float2bfloat16(b);
  unsigned short ux = *(unsigned short*)&x, uy = *(unsigned short*)&y;
  return (unsigned)ux | ((unsigned)uy << 16);
}

// ---------------- dense branch ----------------
__global__ void dense1_kernel(const float* __restrict__ x, const float* __restrict__ h1_w,
                              float* __restrict__ xs1acc) {
  __shared__ float xl[16][64];
  int k0 = blockIdx.y * 64;
  int t = threadIdx.x;
  for (int i = t; i < 16*64; i += 256) {
    int b = i >> 6, kk = i & 63;
    xl[b][kk] = x[b*IN_DIM_ + k0 + kk];
  }
  __syncthreads();
  int c = blockIdx.x*256 + t;
  if (c >= 1000) return;
  float acc[B_];
  #pragma unroll
  for (int b=0;b<B_;b++) acc[b]=0.f;
  #pragma unroll 4
  for (int kk=0; kk<64; kk++) {
    float w = h1_w[(k0+kk)*1000 + c];
    #pragma unroll
    for (int b=0;b<B_;b++) acc[b] += xl[b][kk]*w;
  }
  #pragma unroll
  for (int b=0;b<B_;b++) atomicAdd(&xs1acc[b*1000+c], acc[b]);
}

// applies h1 bias + leaky inline
__global__ void dense2_kernel(const float* __restrict__ xs1acc, const float* __restrict__ h1_b,
                              const float* __restrict__ h2_w, float* __restrict__ xs2acc) {
  int T = blockIdx.x*256+threadIdx.x;
  if (T >= 100*40) return;
  int c = T % 100, kc = T / 100;
  int k0 = kc*25;
  float acc[B_];
  #pragma unroll
  for (int b=0;b<B_;b++) acc[b]=0.f;
  for (int kk=0;kk<25;kk++){
    int k = k0+kk;
    float w = h2_w[k*100 + c];
    float bk = h1_b[k];
    #pragma unroll
    for (int b=0;b<B_;b++){
      float m = xs1acc[b*1000+k] + bk;
      m = (m>0.f)? m : 0.01f*m;
      acc[b] += m*w;
    }
  }
  #pragma unroll
  for (int b=0;b<B_;b++) atomicAdd(&xs2acc[b*100+c], acc[b]);
}

// ---------------- encoder + LN(layer0) fused, wave per node ----------------
// hnb: [N][128] fp16, 256B rows (cols 100..127 zero); h: [N][112] fp16 rows
__global__ void enc_ln_kernel(const float* __restrict__ x, const float* __restrict__ enc_w,
                              const float* __restrict__ enc_b, const float* __restrict__ g0,
                              const float* __restrict__ b0,
                              __half* __restrict__ h, char* __restrict__ hnb) {
  int wid = (blockIdx.x*256 + threadIdx.x) >> 6;
  int lane = threadIdx.x & 63;
  if (wid >= N_) return;
  float xn = x[wid];
  int c0 = 2*lane, c1 = c0+1;
  bool v = c0 < D_;
  float h0=0.f, h1=0.f;
  if (v){ h0 = fmaf(xn, enc_w[c0], enc_b[c0]); h1 = fmaf(xn, enc_w[c1], enc_b[c1]); }
  float s = h0+h1;
  #pragma unroll
  for (int off=32; off; off>>=1) s += __shfl_xor(s, off, 64);
  float mu = s * (1.f/D_);
  float d0 = v? h0-mu : 0.f, d1 = v? h1-mu : 0.f;
  float q = d0*d0 + d1*d1;
  #pragma unroll
  for (int off=32; off; off>>=1) q += __shfl_xor(q, off, 64);
  float rstd = rsqrtf(q*(1.f/D_) + 1e-5f);
  if (c0 < 112) *(__half2*)&h[(size_t)wid*112 + c0] = __floats2half2_rn(h0, h1);
  float n0 = v? fmaxf(fmaf(d0*rstd, g0[c0], b0[c0]), 0.f) : 0.f;
  float n1 = v? fmaxf(fmaf(d1*rstd, g0[c1], b0[c1]), 0.f) : 0.f;
  *(__half2*)(hnb + (size_t)wid*256 + 4*lane) = __floats2half2_rn(n0, n1);
}

// ---------------- CSR build ----------------
__global__ void deg_kernel(const int* __restrict__ dst, int* __restrict__ deg) {
  int e = blockIdx.x*256+threadIdx.x;
  if (e < E_) atomicAdd(&deg[dst[e]], 1);
}

__global__ void scan_kernel(const int* __restrict__ deg, int* __restrict__ row_start) {
  __shared__ int sums[1024];
  int t = threadIdx.x;
  int base = t*64;
  int s = 0;
  for (int j=0;j<64;j++) s += deg[base+j];
  sums[t] = s;
  __syncthreads();
  for (int off=1; off<1024; off<<=1){
    int add = (t>=off)? sums[t-off] : 0;
    __syncthreads();
    sums[t] += add;
    __syncthreads();
  }
  int excl = (t==0)? 0 : sums[t-1];
  int run = excl;
  for (int j=0;j<64;j++){ row_start[base+j] = run; run += deg[base+j]; }
  if (t==1023) row_start[N_] = run;
}

__global__ void scatter_kernel(const int* __restrict__ srcs, const int* __restrict__ dst,
                               const int* __restrict__ row_start, int* __restrict__ cnt,
                               int* __restrict__ sorted_src) {
  int e = blockIdx.x*256+threadIdx.x;
  if (e < E_){
    int d = dst[e];
    int p = row_start[d] + atomicAdd(&cnt[d], 1);
    sorted_src[p] = srcs[e];
  }
}

// ---------------- softmax aggregation, wave per node --------------------
// Indices preloaded lane-parallel (one coalesced load per 64 edges), broadcast
// via __shfl; depth-4 row-gather pipeline depends only on registers.
__global__ void agg_kernel(const char* __restrict__ hnb, const int* __restrict__ row_start,
                           const int* __restrict__ sorted_src, unsigned* __restrict__ u) {
  int wid = (blockIdx.x*256 + threadIdx.x) >> 6;
  int lane = threadIdx.x & 63;
  if (wid >= N_) return;
  int beg = row_start[wid], end = row_start[wid+1];
  int deg = end - beg;
  const char* lanep = hnb + 4*lane;
  float s0=0.f, ws0=0.f, s1=0.f, ws1=0.f;
  for (int chunk=0; chunk<deg; chunk+=64){
    int cnt = deg - chunk; if (cnt > 64) cnt = 64;
    int cidx = (chunk + lane < deg) ? sorted_src[beg + chunk + lane] : 0;
    __half2 r0={}, r1={}, r2={}, r3={};
    if (0 < cnt) r0 = *(const __half2*)(lanep + (size_t)__shfl(cidx,0)*256);
    if (1 < cnt) r1 = *(const __half2*)(lanep + (size_t)__shfl(cidx,1)*256);
    if (2 < cnt) r2 = *(const __half2*)(lanep + (size_t)__shfl(cidx,2)*256);
    if (3 < cnt) r3 = *(const __half2*)(lanep + (size_t)__shfl(cidx,3)*256);
    for (int j=0; j<cnt; j+=4){
      __half2 n0={}, n1={}, n2={}, n3={};
      if (j+4 < cnt) n0 = *(const __half2*)(lanep + (size_t)__shfl(cidx,j+4)*256);
      if (j+5 < cnt) n1 = *(const __half2*)(lanep + (size_t)__shfl(cidx,j+5)*256);
      if (j+6 < cnt) n2 = *(const __half2*)(lanep + (size_t)__shfl(cidx,j+6)*256);
      if (j+7 < cnt) n3 = *(const __half2*)(lanep + (size_t)__shfl(cidx,j+7)*256);
      {
        float v0 = __low2float(r0)+EPS_, v1 = __high2float(r0)+EPS_;
        float e0 = __expf(v0), e1 = __expf(v1);
        s0 += e0; ws0 = fmaf(e0, v0, ws0);
        s1 += e1; ws1 = fmaf(e1, v1, ws1);
      }
      if (j+1 < cnt){
        float v0 = __low2float(r1)+EPS_, v1 = __high2float(r1)+EPS_;
        float e0 = __expf(v0), e1 = __expf(v1);
        s0 += e0; ws0 = fmaf(e0, v0, ws0);
        s1 += e1; ws1 = fmaf(e1, v1, ws1);
      }
      if (j+2 < cnt){
        float v0 = __low2float(r2)+EPS_, v1 = __high2float(r2)+EPS_;
        float e0 = __expf(v0), e1 = __expf(v1);
        s0 += e0; ws0 = fmaf(e0, v0, ws0);
        s1 += e1; ws1 = fmaf(e1, v1, ws1);
      }
      if (j+3 < cnt){
        float v0 = __low2float(r3)+EPS_, v1 = __high2float(r3)+EPS_;
        float e0 = __expf(v0), e1 = __expf(v1);
        s0 += e0; ws0 = fmaf(e0, v0, ws0);
        s1 += e1; ws1 = fmaf(e1, v1, ws1);
      }
      r0=n0; r1=n1; r2=n2; r3=n3;
    }
  }
  __half2 own = *(const __half2*)(lanep + (size_t)wid*256);
  float u0 = ((deg>0)? ws0/s0 : 0.f) + __low2float(own);
  float u1 = ((deg>0)? ws1/s1 : 0.f) + __high2float(own);
  if (lane >= 50) { u0 = 0.f; u1 = 0.f; }     // zero K-pad cols 100..127
  u[(size_t)wid*64 + lane] = pack_bf16x2(u0, u1);
}

// ---------------- weight prep: transpose+pad+bf16 once ----------------
__global__ void prep_weights(const float* __restrict__ w1, const float* __restrict__ w2,
                             __hip_bfloat16* __restrict__ w1T, __hip_bfloat16* __restrict__ w2T) {
  int idx = blockIdx.x*256 + threadIdx.x;
  if (idx < L_*224*128) {
    int l = idx / (224*128);
    int rem = idx % (224*128);
    int col = rem / 128, k = rem % 128;
    float v = (col < H_ && k < D_) ? w1[(l*D_ + k)*H_ + col] : 0.f;
    w1T[idx] = __float2bfloat16(v);
  }
  if (idx < L_*112*224) {
    int l = idx / (112*224);
    int rem = idx % (112*224);
    int col = rem / 224, k = rem % 224;
    float v = (col < D_ && k < H_) ? w2[(l*H_ + k)*D_ + col] : 0.f;
    w2T[idx] = __float2bfloat16(v);
  }
}

// ---------------- GEMM1: z = relu(bn(u @ w1 + b1)), bf16 MFMA -------------
__global__ __launch_bounds__(256,2) void gemm1_kernel(
    const __hip_bfloat16* __restrict__ u, const __hip_bfloat16* __restrict__ w1T,
    const float* __restrict__ b1, const float* __restrict__ bng, const float* __restrict__ bnb,
    char* __restrict__ z) {
  __shared__ __align__(16) char lds[288*272];   // u: 64 rows + w1T: 224 rows
  char* uL = lds;
  char* wL = lds + 64*272;
  int t = threadIdx.x;
  size_t row0 = (size_t)blockIdx.x * 64;
  const char* ug = (const char*)(u + row0*128);
  #pragma unroll
  for (int c = t; c < 1024; c += 256) {
    int r = c >> 4, sb = (c & 15) << 4;
    *(float4*)(uL + r*272 + sb) = *(const float4*)(ug + (size_t)r*256 + sb);
  }
  const char* wg = (const char*)w1T;
  #pragma unroll
  for (int c = t; c < 3584; c += 256) {
    int r = c >> 4, sb = (c & 15) << 4;
    *(float4*)(wL + r*272 + sb) = *(const float4*)(wg + (size_t)r*256 + sb);
  }
  __syncthreads();
  int wave = t >> 6, lane = t & 63;
  int l15 = lane & 15;
  int kgb = (lane >> 4) << 4;
  int ar = wave*16 + l15;
  f32x4 acc[14];
  #pragma unroll
  for (int n=0;n<14;n++) acc[n] = (f32x4){0.f,0.f,0.f,0.f};
  #pragma unroll
  for (int ks=0; ks<4; ks++) {
    int kb = ks*64 + kgb;
    bf16x8s a = *(const bf16x8s*)(uL + ar*272 + kb);
    #pragma unroll
    for (int n=0;n<14;n++) {
      bf16x8s b = *(const bf16x8s*)(wL + (n*16 + l15)*272 + kb);
      acc[n] = __builtin_amdgcn_mfma_f32_16x16x32_bf16(a, b, acc[n], 0, 0, 0);
    }
  }
  size_t rbase = row0 + wave*16 + ((lane>>4)<<2);
  #pragma unroll
  for (int n=0;n<14;n++) {
    int col = n*16 + l15;
    float bias = (col < H_) ? b1[col] : 0.f;
    float g    = (col < H_) ? bng[col] : 0.f;
    float bb   = (col < H_) ? bnb[col] : 0.f;
    #pragma unroll
    for (int r=0;r<4;r++) {
      float v = fmaxf((acc[n][r] + bias)*g + bb, 0.f);
      if (col >= H_) v = 0.f;
      *(__hip_bfloat16*)(z + (rbase + r)*448 + 2*col) = __float2bfloat16(v);
    }
  }
}

// ---------------- GEMM2 (+LN epilogue, or +pool on last layer) --------------
// h fp16 [N][112]. LAST=0: h += z@w2+b2, hnb = fp16(relu(LN(h))).
// LAST=1: pooled += column sums of h_new (h not stored).
template<int LAST>
__global__ __launch_bounds__(256,2) void gemm2_kernel(
    const char* __restrict__ z, const __hip_bfloat16* __restrict__ w2T,
    const float* __restrict__ b2, __half* __restrict__ h,
    const float* __restrict__ lng, const float* __restrict__ lnb,
    char* __restrict__ hnb, float* __restrict__ pooled) {
  __shared__ __align__(16) char lds[176*464];   // z: 64 rows + w2T: 112 rows
  char* zL = lds;
  char* wL = lds + 64*464;
  int t = threadIdx.x;
  size_t row0 = (size_t)blockIdx.x * 64;
  const char* zg = z + row0*448;
  for (int c = t; c < 1792; c += 256) {
    int r = c / 28, sb = (c - r*28) << 4;
    *(float4*)(zL + r*464 + sb) = *(const float4*)(zg + (size_t)r*448 + sb);
  }
  const char* wg = (const char*)w2T;
  for (int c = t; c < 3136; c += 256) {
    int r = c / 28, sb = (c - r*28) << 4;
    *(float4*)(wL + r*464 + sb) = *(const float4*)(wg + (size_t)r*448 + sb);
  }
  __syncthreads();
  int wave = t >> 6, lane = t & 63;
  int l15 = lane & 15;
  int kgb = (lane >> 4) << 4;
  int ar = wave*16 + l15;
  f32x4 acc[7];
  #pragma unroll
  for (int n=0;n<7;n++) acc[n] = (f32x4){0.f,0.f,0.f,0.f};
  #pragma unroll
  for (int ks=0; ks<7; ks++) {
    int kb = ks*64 + kgb;
    bf16x8s a = *(const bf16x8s*)(zL + ar*464 + kb);
    #pragma unroll
    for (int n=0;n<7;n++) {
      bf16x8s b = *(const bf16x8s*)(wL + (n*16 + l15)*464 + kb);
      acc[n] = __builtin_amdgcn_mfma_f32_16x16x32_bf16(a, b, acc[n], 0, 0, 0);
    }
  }
  size_t rbase = row0 + wave*16 + ((lane>>4)<<2);

  float x_[7][4];
  float sum[4]  = {0,0,0,0};
  float sum2[4] = {0,0,0,0};
  float psum[7] = {0,0,0,0,0,0,0};
  #pragma unroll
  for (int n=0;n<7;n++) {
    int col = n*16 + l15;
    bool valid = col < D_;
    float bias = valid ? b2[col] : 0.f;
    #pragma unroll
    for (int r=0;r<4;r++) {
      float xv = 0.f;
      if (valid) xv = acc[n][r] + bias + __half2float(h[(rbase + r)*112 + col]);
      x_[n][r] = xv;
      if (LAST) {
        psum[n] += xv;
      } else {
        sum[r] += xv; sum2[r] += xv*xv;
        if (valid) h[(rbase + r)*112 + col] = __float2half(xv);
      }
    }
  }

  if (LAST) {
    #pragma unroll
    for (int n=0;n<7;n++) {
      psum[n] += __shfl_xor(psum[n], 16, 64);
      psum[n] += __shfl_xor(psum[n], 32, 64);
    }
    __syncthreads();
    float* ps = (float*)lds;             // [4][112]
    if (lane < 16) {
      #pragma unroll
      for (int n=0;n<7;n++) ps[wave*112 + n*16 + l15] = psum[n];
    }
    __syncthreads();
    if (t < D_) {
      float v = ps[t] + ps[112+t] + ps[224+t] + ps[336+t];
      int b = (int)(row0 >> 12);        // row0 / 4096
      atomicAdd(&pooled[b*D_ + t], v);
    }
  } else {
    #pragma unroll
    for (int r=0;r<4;r++) {
      float s = sum[r], s2 = sum2[r];
      #pragma unroll
      for (int m=1;m<16;m<<=1) { s += __shfl_xor(s, m, 16); s2 += __shfl_xor(s2, m, 16); }
      sum[r] = s; sum2[r] = s2;
    }
    #pragma unroll
    for (int n=0;n<7;n++) {
      int col = n*16 + l15;
      float g  = (col < D_) ? lng[col] : 0.f;
      float be = (col < D_) ? lnb[col] : 0.f;
      #pragma unroll
      for (int r=0;r<4;r++) {
        float mu = sum[r]*(1.f/D_);
        float var = sum2[r]*(1.f/D_) - mu*mu;
        float rstd = rsqrtf(var + 1e-5f);
        float hv = fmaxf(fmaf((x_[n][r]-mu)*rstd, g, be), 0.f);
        if (col >= D_) hv = 0.f;
        *(__half*)(hnb + (rbase + r)*256 + 2*col) = __float2half(hv);
      }
    }
    {
      int col = 112 + l15;
      __half zh = __float2half(0.f);
      #pragma unroll
      for (int r=0;r<4;r++)
        *(__half*)(hnb + (rbase + r)*256 + 2*col) = zh;
    }
  }
}

// ---------------- head (dense2 bias+leaky folded in) ----------------
__global__ void final_kernel(const float* __restrict__ xs2acc, const float* __restrict__ h2_b,
                             const float* __restrict__ pooled,
                             const float* __restrict__ dec_w, const float* __restrict__ dec_b,
                             float* __restrict__ out) {
  __shared__ float red[128];
  int t = threadIdx.x;
  for (int b=0;b<B_;b++){
    float v = 0.f;
    if (t < D_) {
      float xs = xs2acc[b*D_+t] + h2_b[t];
      xs = (xs>0.f)? xs : 0.01f*xs;
      v = (0.5f*xs + (0.5f/IN_DIM_)*pooled[b*D_+t]) * dec_w[t];
    }
    red[t] = v;
    __syncthreads();
    for (int off=64; off; off>>=1){
      if (t < off) red[t] += red[t+off];
      __syncthreads();
    }
    if (t==0) out[b] = red[0] + dec_b[0];
    __syncthreads();
  }
}

extern "C" void kernel_launch(void* const* d_in, const int* in_sizes, int n_in,
                              void* d_out, int out_size, void* d_ws, size_t ws_size,
                              hipStream_t stream) {
  const float* x      = (const float*)d_in[0];
  const int*   eidx   = (const int*)d_in[1];
  const float* enc_w  = (const float*)d_in[3];
  const float* enc_b  = (const float*)d_in[4];
  const float* h1_w   = (const float*)d_in[5];
  const float* h1_b   = (const float*)d_in[6];
  const float* h2_w   = (const float*)d_in[7];
  const float* h2_b   = (const float*)d_in[8];
  const float* ln_g   = (const float*)d_in[9];
  const float* ln_b   = (const float*)d_in[10];
  const float* w1     = (const float*)d_in[11];
  const float* b1     = (const float*)d_in[12];
  const float* bn_g   = (const float*)d_in[13];
  const float* bn_b   = (const float*)d_in[14];
  const float* w2     = (const float*)d_in[15];
  const float* b2     = (const float*)d_in[16];
  const float* dec_w  = (const float*)d_in[17];
  const float* dec_b  = (const float*)d_in[18];
  float* out = (float*)d_out;

  char* ws = (char*)d_ws;
  size_t off = 0;
  auto alloc = [&](size_t bytes)->char* {
    char* p = ws + off;
    off += (bytes + 255) & ~(size_t)255;
    return p;
  };
  __half* h     = (__half*)alloc((size_t)N_*112*2);          // 14.7 MB
  char*  hnb    = alloc((size_t)N_*256);                     // 16.8 MB ([N][128] fp16)
  char*  z      = alloc((size_t)N_*448);                     // 29.4 MB ([N][224] bf16)
  unsigned* u   = (unsigned*)alloc((size_t)N_*64*4);         // 16.8 MB ([N][128] bf16)
  __hip_bfloat16* w1T = (__hip_bfloat16*)alloc((size_t)L_*224*128*2);
  __hip_bfloat16* w2T = (__hip_bfloat16*)alloc((size_t)L_*112*224*2);
  float* xs1    = (float*)alloc(16*1000*4);
  float* xs2    = (float*)alloc(16*100*4);
  float* pooled = (float*)alloc(16*100*4);
  int* deg        = (int*)alloc(N_*4);
  int* row_start  = (int*)alloc((N_+1)*4);
  int* cnt        = (int*)alloc(N_*4);
  int* sorted_src = (int*)alloc(E_*4);

  const int* srcs = eidx;
  const int* dsts = eidx + E_;

  hipMemsetAsync(xs1, 0, 16*1000*4, stream);
  hipMemsetAsync(xs2, 0, 16*100*4, stream);
  hipMemsetAsync(pooled, 0, 16*100*4, stream);
  hipMemsetAsync(deg, 0, N_*4, stream);
  hipMemsetAsync(cnt, 0, N_*4, stream);

  {
    dim3 g1(4, 64);
    dense1_kernel<<<g1, 256, 0, stream>>>(x, h1_w, xs1);
  }
  dense2_kernel<<<16, 256, 0, stream>>>(xs1, h1_b, h2_w, xs2);

  enc_ln_kernel<<<N_/4, 256, 0, stream>>>(x, enc_w, enc_b, ln_g, ln_b, h, hnb);

  deg_kernel<<<E_/256, 256, 0, stream>>>(dsts, deg);
  scan_kernel<<<1, 1024, 0, stream>>>(deg, row_start);
  scatter_kernel<<<E_/256, 256, 0, stream>>>(srcs, dsts, row_start, cnt, sorted_src);

  prep_weights<<<(L_*224*128+255)/256, 256, 0, stream>>>(w1, w2, w1T, w2T);

  for (int i=0;i<L_;i++){
    agg_kernel<<<N_/4, 256, 0, stream>>>(hnb, row_start, sorted_src, u);
    gemm1_kernel<<<N_/64, 256, 0, stream>>>((const __hip_bfloat16*)u,
                                            w1T + (size_t)i*224*128, b1 + i*H_,
                                            bn_g + i*H_, bn_b + i*H_, z);
    if (i < L_-1) {
      gemm2_kernel<0><<<N_/64, 256, 0, stream>>>(z, w2T + (size_t)i*112*224, b2 + i*D_,
                                                 h, ln_g + (i+1)*D_, ln_b + (i+1)*D_,
                                                 hnb, pooled);
    } else {
      gemm2_kernel<1><<<N_/64, 256, 0, stream>>>(z, w2T + (size_t)i*112*224, b2 + i*D_,
                                                 h, nullptr, nullptr, hnb, pooled);
    }
  }

  final_kernel<<<1, 128, 0, stream>>>(xs2, h2_b, pooled, dec_w, dec_b, out);
}

// Round 10
// 460.315 us; speedup vs baseline: 1.3397x; 1.0009x over previous
//
#include <hip/hip_runtime.h>
#include <hip/hip_bf16.h>
#include <hip/hip_fp16.h>
#include <math.h>

#define B_ 16
#define IN_DIM_ 4096
#define D_ 100
#define H_ 200
#define L_ 4
#define N_ (B_*IN_DIM_)     // 65536
#define E_ (8*B_*IN_DIM_)   // 524288
#define EPS_ 1e-7f

typedef __attribute__((ext_vector_type(8))) short bf16x8s;  // 8 bf16 (4 VGPRs)
typedef __attribute__((ext_vector_type(4))) float f32x4;

__device__ inline unsigned pack_bf16x2(float a, float b){
  __hip_bfloat16 x = __float2bfloat16(a), y = __float2bfloat16(b);
  unsigned short ux = *(unsigned short*)&x, uy = *(unsigned short*)&y;
  return (unsigned)ux | ((unsigned)uy << 16);
}
__device__ inline __half2 u2h(unsigned v){ return *(__half2*)&v; }

// ---------------- dense branch ----------------
__global__ void dense1_kernel(const float* __restrict__ x, const float* __restrict__ h1_w,
                              float* __restrict__ xs1acc) {
  __shared__ float xl[16][64];
  int k0 = blockIdx.y * 64;
  int t = threadIdx.x;
  for (int i = t; i < 16*64; i += 256) {
    int b = i >> 6, kk = i & 63;
    xl[b][kk] = x[b*IN_DIM_ + k0 + kk];
  }
  __syncthreads();
  int c = blockIdx.x*256 + t;
  if (c >= 1000) return;
  float acc[B_];
  #pragma unroll
  for (int b=0;b<B_;b++) acc[b]=0.f;
  #pragma unroll 4
  for (int kk=0; kk<64; kk++) {
    float w = h1_w[(k0+kk)*1000 + c];
    #pragma unroll
    for (int b=0;b<B_;b++) acc[b] += xl[b][kk]*w;
  }
  #pragma unroll
  for (int b=0;b<B_;b++) atomicAdd(&xs1acc[b*1000+c], acc[b]);
}

// applies h1 bias + leaky inline
__global__ void dense2_kernel(const float* __restrict__ xs1acc, const float* __restrict__ h1_b,
                              const float* __restrict__ h2_w, float* __restrict__ xs2acc) {
  int T = blockIdx.x*256+threadIdx.x;
  if (T >= 100*40) return;
  int c = T % 100, kc = T / 100;
  int k0 = kc*25;
  float acc[B_];
  #pragma unroll
  for (int b=0;b<B_;b++) acc[b]=0.f;
  for (int kk=0;kk<25;kk++){
    int k = k0+kk;
    float w = h2_w[k*100 + c];
    float bk = h1_b[k];
    #pragma unroll
    for (int b=0;b<B_;b++){
      float m = xs1acc[b*1000+k] + bk;
      m = (m>0.f)? m : 0.01f*m;
      acc[b] += m*w;
    }
  }
  #pragma unroll
  for (int b=0;b<B_;b++) atomicAdd(&xs2acc[b*100+c], acc[b]);
}

// ---------------- encoder + LN(layer0) fused, wave per node ----------------
// hnb: [N][128] fp16, 256B rows (cols 100..127 zero); h: [N][112] fp16 rows
__global__ void enc_ln_kernel(const float* __restrict__ x, const float* __restrict__ enc_w,
                              const float* __restrict__ enc_b, const float* __restrict__ g0,
                              const float* __restrict__ b0,
                              __half* __restrict__ h, char* __restrict__ hnb) {
  int wid = (blockIdx.x*256 + threadIdx.x) >> 6;
  int lane = threadIdx.x & 63;
  if (wid >= N_) return;
  float xn = x[wid];
  int c0 = 2*lane, c1 = c0+1;
  bool v = c0 < D_;
  float h0=0.f, h1=0.f;
  if (v){ h0 = fmaf(xn, enc_w[c0], enc_b[c0]); h1 = fmaf(xn, enc_w[c1], enc_b[c1]); }
  float s = h0+h1;
  #pragma unroll
  for (int off=32; off; off>>=1) s += __shfl_xor(s, off, 64);
  float mu = s * (1.f/D_);
  float d0 = v? h0-mu : 0.f, d1 = v? h1-mu : 0.f;
  float q = d0*d0 + d1*d1;
  #pragma unroll
  for (int off=32; off; off>>=1) q += __shfl_xor(q, off, 64);
  float rstd = rsqrtf(q*(1.f/D_) + 1e-5f);
  if (c0 < 112) *(__half2*)&h[(size_t)wid*112 + c0] = __floats2half2_rn(h0, h1);
  float n0 = v? fmaxf(fmaf(d0*rstd, g0[c0], b0[c0]), 0.f) : 0.f;
  float n1 = v? fmaxf(fmaf(d1*rstd, g0[c1], b0[c1]), 0.f) : 0.f;
  *(__half2*)(hnb + (size_t)wid*256 + 4*lane) = __floats2half2_rn(n0, n1);
}

// ---------------- CSR build ----------------
__global__ void deg_kernel(const int* __restrict__ dst, int* __restrict__ deg) {
  int e = blockIdx.x*256+threadIdx.x;
  if (e < E_) atomicAdd(&deg[dst[e]], 1);
}

__global__ void scan_kernel(const int* __restrict__ deg, int* __restrict__ row_start) {
  __shared__ int sums[1024];
  int t = threadIdx.x;
  int base = t*64;
  int s = 0;
  for (int j=0;j<64;j++) s += deg[base+j];
  sums[t] = s;
  __syncthreads();
  for (int off=1; off<1024; off<<=1){
    int add = (t>=off)? sums[t-off] : 0;
    __syncthreads();
    sums[t] += add;
    __syncthreads();
  }
  int excl = (t==0)? 0 : sums[t-1];
  int run = excl;
  for (int j=0;j<64;j++){ row_start[base+j] = run; run += deg[base+j]; }
  if (t==1023) row_start[N_] = run;
}

__global__ void scatter_kernel(const int* __restrict__ srcs, const int* __restrict__ dst,
                               const int* __restrict__ row_start, int* __restrict__ cnt,
                               int* __restrict__ sorted_src) {
  int e = blockIdx.x*256+threadIdx.x;
  if (e < E_){
    int d = dst[e];
    int p = row_start[d] + atomicAdd(&cnt[d], 1);
    sorted_src[p] = srcs[e];
  }
}

// ---------------- softmax aggregation: 2 nodes/wave, 8B/lane ---------------
// 32 lanes per node (4 cols/lane); one wave-load serves 2 edge-visits.
// Indices preloaded lane-parallel per 32-edge chunk, broadcast via __shfl.
__global__ void agg_kernel(const char* __restrict__ hnb, const int* __restrict__ row_start,
                           const int* __restrict__ sorted_src, unsigned* __restrict__ u) {
  int gw = (blockIdx.x*256 + threadIdx.x) >> 6;   // wave id: 0..N/2-1
  int lane = threadIdx.x & 63;
  int lpos = lane & 31;
  int gbase = lane & 32;                          // 0 or 32: group base lane
  int node = gw*2 + (lane >> 5);
  int beg = row_start[node];
  int deg = row_start[node+1] - beg;
  int mdeg = deg;
  #pragma unroll
  for (int m=1; m<64; m<<=1) { int o = __shfl_xor(mdeg, m, 64); mdeg = mdeg > o ? mdeg : o; }
  const char* lanep = hnb + 8*lpos;
  float s0=0.f,s1=0.f,s2=0.f,s3=0.f, w0=0.f,w1=0.f,w2=0.f,w3=0.f;

#define CONSUME_(R) { \
    __half2 ha = u2h(R.x), hb = u2h(R.y); \
    float v0=__low2float(ha)+EPS_, v1=__high2float(ha)+EPS_; \
    float v2=__low2float(hb)+EPS_, v3=__high2float(hb)+EPS_; \
    float e0=__expf(v0), e1=__expf(v1), e2=__expf(v2), e3=__expf(v3); \
    s0+=e0; w0=fmaf(e0,v0,w0); s1+=e1; w1=fmaf(e1,v1,w1); \
    s2+=e2; w2=fmaf(e2,v2,w2); s3+=e3; w3=fmaf(e3,v3,w3); }

  for (int cb=0; cb<mdeg; cb+=32){
    int cidx = (cb + lpos < deg) ? sorted_src[beg + cb + lpos] : 0;
    int cnt = mdeg - cb; if (cnt > 32) cnt = 32;          // wave-uniform
    int grem = deg - cb;                                   // per-group remaining
    int glim = grem < cnt ? grem : cnt; if (glim < 0) glim = 0;
    uint2 r0={0,0}, r1={0,0}, r2={0,0}, r3={0,0};
    if (0 < glim) r0 = *(const uint2*)(lanep + (size_t)__shfl(cidx, gbase+0)*256);
    if (1 < glim) r1 = *(const uint2*)(lanep + (size_t)__shfl(cidx, gbase+1)*256);
    if (2 < glim) r2 = *(const uint2*)(lanep + (size_t)__shfl(cidx, gbase+2)*256);
    if (3 < glim) r3 = *(const uint2*)(lanep + (size_t)__shfl(cidx, gbase+3)*256);
    for (int j=0; j<cnt; j+=4){
      uint2 n0={0,0}, n1={0,0}, n2={0,0}, n3={0,0};
      if (j+4 < glim) n0 = *(const uint2*)(lanep + (size_t)__shfl(cidx, gbase+j+4)*256);
      if (j+5 < glim) n1 = *(const uint2*)(lanep + (size_t)__shfl(cidx, gbase+j+5)*256);
      if (j+6 < glim) n2 = *(const uint2*)(lanep + (size_t)__shfl(cidx, gbase+j+6)*256);
      if (j+7 < glim) n3 = *(const uint2*)(lanep + (size_t)__shfl(cidx, gbase+j+7)*256);
      if (j   < glim) CONSUME_(r0);
      if (j+1 < glim) CONSUME_(r1);
      if (j+2 < glim) CONSUME_(r2);
      if (j+3 < glim) CONSUME_(r3);
      r0=n0; r1=n1; r2=n2; r3=n3;
    }
  }
#undef CONSUME_

  uint2 own = *(const uint2*)(lanep + (size_t)node*256);
  __half2 oa = u2h(own.x), ob = u2h(own.y);
  float u0 = ((deg>0)? w0/s0 : 0.f) + __low2float(oa);
  float u1 = ((deg>0)? w1/s1 : 0.f) + __high2float(oa);
  float u2 = ((deg>0)? w2/s2 : 0.f) + __low2float(ob);
  float u3 = ((deg>0)? w3/s3 : 0.f) + __high2float(ob);
  if (lpos >= 25) { u0=0.f; u1=0.f; u2=0.f; u3=0.f; }   // zero K-pad cols 100..127
  uint2 outv; outv.x = pack_bf16x2(u0,u1); outv.y = pack_bf16x2(u2,u3);
  *(uint2*)((char*)u + (size_t)node*256 + 8*lpos) = outv;
}

// ---------------- weight prep: transpose+pad+bf16 once ----------------
__global__ void prep_weights(const float* __restrict__ w1, const float* __restrict__ w2,
                             __hip_bfloat16* __restrict__ w1T, __hip_bfloat16* __restrict__ w2T) {
  int idx = blockIdx.x*256 + threadIdx.x;
  if (idx < L_*224*128) {
    int l = idx / (224*128);
    int rem = idx % (224*128);
    int col = rem / 128, k = rem % 128;
    float v = (col < H_ && k < D_) ? w1[(l*D_ + k)*H_ + col] : 0.f;
    w1T[idx] = __float2bfloat16(v);
  }
  if (idx < L_*112*224) {
    int l = idx / (112*224);
    int rem = idx % (112*224);
    int col = rem / 224, k = rem % 224;
    float v = (col < D_ && k < H_) ? w2[(l*H_ + k)*D_ + col] : 0.f;
    w2T[idx] = __float2bfloat16(v);
  }
}

// ---------------- GEMM1: z = relu(bn(u @ w1 + b1)), bf16 MFMA -------------
__global__ __launch_bounds__(256,2) void gemm1_kernel(
    const __hip_bfloat16* __restrict__ u, const __hip_bfloat16* __restrict__ w1T,
    const float* __restrict__ b1, const float* __restrict__ bng, const float* __restrict__ bnb,
    char* __restrict__ z) {
  __shared__ __align__(16) char lds[288*272];   // u: 64 rows + w1T: 224 rows
  char* uL = lds;
  char* wL = lds + 64*272;
  int t = threadIdx.x;
  size_t row0 = (size_t)blockIdx.x * 64;
  const char* ug = (const char*)(u + row0*128);
  #pragma unroll
  for (int c = t; c < 1024; c += 256) {
    int r = c >> 4, sb = (c & 15) << 4;
    *(float4*)(uL + r*272 + sb) = *(const float4*)(ug + (size_t)r*256 + sb);
  }
  const char* wg = (const char*)w1T;
  #pragma unroll
  for (int c = t; c < 3584; c += 256) {
    int r = c >> 4, sb = (c & 15) << 4;
    *(float4*)(wL + r*272 + sb) = *(const float4*)(wg + (size_t)r*256 + sb);
  }
  __syncthreads();
  int wave = t >> 6, lane = t & 63;
  int l15 = lane & 15;
  int kgb = (lane >> 4) << 4;
  int ar = wave*16 + l15;
  f32x4 acc[14];
  #pragma unroll
  for (int n=0;n<14;n++) acc[n] = (f32x4){0.f,0.f,0.f,0.f};
  #pragma unroll
  for (int ks=0; ks<4; ks++) {
    int kb = ks*64 + kgb;
    bf16x8s a = *(const bf16x8s*)(uL + ar*272 + kb);
    #pragma unroll
    for (int n=0;n<14;n++) {
      bf16x8s b = *(const bf16x8s*)(wL + (n*16 + l15)*272 + kb);
      acc[n] = __builtin_amdgcn_mfma_f32_16x16x32_bf16(a, b, acc[n], 0, 0, 0);
    }
  }
  size_t rbase = row0 + wave*16 + ((lane>>4)<<2);
  #pragma unroll
  for (int n=0;n<14;n++) {
    int col = n*16 + l15;
    float bias = (col < H_) ? b1[col] : 0.f;
    float g    = (col < H_) ? bng[col] : 0.f;
    float bb   = (col < H_) ? bnb[col] : 0.f;
    #pragma unroll
    for (int r=0;r<4;r++) {
      float v = fmaxf((acc[n][r] + bias)*g + bb, 0.f);
      if (col >= H_) v = 0.f;
      *(__hip_bfloat16*)(z + (rbase + r)*448 + 2*col) = __float2bfloat16(v);
    }
  }
}

// ---------------- GEMM2 (+LN epilogue, or +pool on last layer) --------------
// h fp16 [N][112]. LAST=0: h += z@w2+b2, hnb = fp16(relu(LN(h))).
// LAST=1: pooled += column sums of h_new (h not stored).
template<int LAST>
__global__ __launch_bounds__(256,2) void gemm2_kernel(
    const char* __restrict__ z, const __hip_bfloat16* __restrict__ w2T,
    const float* __restrict__ b2, __half* __restrict__ h,
    const float* __restrict__ lng, const float* __restrict__ lnb,
    char* __restrict__ hnb, float* __restrict__ pooled) {
  __shared__ __align__(16) char lds[176*464];   // z: 64 rows + w2T: 112 rows
  char* zL = lds;
  char* wL = lds + 64*464;
  int t = threadIdx.x;
  size_t row0 = (size_t)blockIdx.x * 64;
  const char* zg = z + row0*448;
  for (int c = t; c < 1792; c += 256) {
    int r = c / 28, sb = (c - r*28) << 4;
    *(float4*)(zL + r*464 + sb) = *(const float4*)(zg + (size_t)r*448 + sb);
  }
  const char* wg = (const char*)w2T;
  for (int c = t; c < 3136; c += 256) {
    int r = c / 28, sb = (c - r*28) << 4;
    *(float4*)(wL + r*464 + sb) = *(const float4*)(wg + (size_t)r*448 + sb);
  }
  __syncthreads();
  int wave = t >> 6, lane = t & 63;
  int l15 = lane & 15;
  int kgb = (lane >> 4) << 4;
  int ar = wave*16 + l15;
  f32x4 acc[7];
  #pragma unroll
  for (int n=0;n<7;n++) acc[n] = (f32x4){0.f,0.f,0.f,0.f};
  #pragma unroll
  for (int ks=0; ks<7; ks++) {
    int kb = ks*64 + kgb;
    bf16x8s a = *(const bf16x8s*)(zL + ar*464 + kb);
    #pragma unroll
    for (int n=0;n<7;n++) {
      bf16x8s b = *(const bf16x8s*)(wL + (n*16 + l15)*464 + kb);
      acc[n] = __builtin_amdgcn_mfma_f32_16x16x32_bf16(a, b, acc[n], 0, 0, 0);
    }
  }
  size_t rbase = row0 + wave*16 + ((lane>>4)<<2);

  float x_[7][4];
  float sum[4]  = {0,0,0,0};
  float sum2[4] = {0,0,0,0};
  float psum[7] = {0,0,0,0,0,0,0};
  #pragma unroll
  for (int n=0;n<7;n++) {
    int col = n*16 + l15;
    bool valid = col < D_;
    float bias = valid ? b2[col] : 0.f;
    #pragma unroll
    for (int r=0;r<4;r++) {
      float xv = 0.f;
      if (valid) xv = acc[n][r] + bias + __half2float(h[(rbase + r)*112 + col]);
      x_[n][r] = xv;
      if (LAST) {
        psum[n] += xv;
      } else {
        sum[r] += xv; sum2[r] += xv*xv;
        if (valid) h[(rbase + r)*112 + col] = __float2half(xv);
      }
    }
  }

  if (LAST) {
    #pragma unroll
    for (int n=0;n<7;n++) {
      psum[n] += __shfl_xor(psum[n], 16, 64);
      psum[n] += __shfl_xor(psum[n], 32, 64);
    }
    __syncthreads();
    float* ps = (float*)lds;             // [4][112]
    if (lane < 16) {
      #pragma unroll
      for (int n=0;n<7;n++) ps[wave*112 + n*16 + l15] = psum[n];
    }
    __syncthreads();
    if (t < D_) {
      float v = ps[t] + ps[112+t] + ps[224+t] + ps[336+t];
      int b = (int)(row0 >> 12);        // row0 / 4096
      atomicAdd(&pooled[b*D_ + t], v);
    }
  } else {
    #pragma unroll
    for (int r=0;r<4;r++) {
      float s = sum[r], s2 = sum2[r];
      #pragma unroll
      for (int m=1;m<16;m<<=1) { s += __shfl_xor(s, m, 16); s2 += __shfl_xor(s2, m, 16); }
      sum[r] = s; sum2[r] = s2;
    }
    #pragma unroll
    for (int n=0;n<7;n++) {
      int col = n*16 + l15;
      float g  = (col < D_) ? lng[col] : 0.f;
      float be = (col < D_) ? lnb[col] : 0.f;
      #pragma unroll
      for (int r=0;r<4;r++) {
        float mu = sum[r]*(1.f/D_);
        float var = sum2[r]*(1.f/D_) - mu*mu;
        float rstd = rsqrtf(var + 1e-5f);
        float hv = fmaxf(fmaf((x_[n][r]-mu)*rstd, g, be), 0.f);
        if (col >= D_) hv = 0.f;
        *(__half*)(hnb + (rbase + r)*256 + 2*col) = __float2half(hv);
      }
    }
    {
      int col = 112 + l15;
      __half zh = __float2half(0.f);
      #pragma unroll
      for (int r=0;r<4;r++)
        *(__half*)(hnb + (rbase + r)*256 + 2*col) = zh;
    }
  }
}

// ---------------- head (dense2 bias+leaky folded in) ----------------
__global__ void final_kernel(const float* __restrict__ xs2acc, const float* __restrict__ h2_b,
                             const float* __restrict__ pooled,
                             const float* __restrict__ dec_w, const float* __restrict__ dec_b,
                             float* __restrict__ out) {
  __shared__ float red[128];
  int t = threadIdx.x;
  for (int b=0;b<B_;b++){
    float v = 0.f;
    if (t < D_) {
      float xs = xs2acc[b*D_+t] + h2_b[t];
      xs = (xs>0.f)? xs : 0.01f*xs;
      v = (0.5f*xs + (0.5f/IN_DIM_)*pooled[b*D_+t]) * dec_w[t];
    }
    red[t] = v;
    __syncthreads();
    for (int off=64; off; off>>=1){
      if (t < off) red[t] += red[t+off];
      __syncthreads();
    }
    if (t==0) out[b] = red[0] + dec_b[0];
    __syncthreads();
  }
}

extern "C" void kernel_launch(void* const* d_in, const int* in_sizes, int n_in,
                              void* d_out, int out_size, void* d_ws, size_t ws_size,
                              hipStream_t stream) {
  const float* x      = (const float*)d_in[0];
  const int*   eidx   = (const int*)d_in[1];
  const float* enc_w  = (const float*)d_in[3];
  const float* enc_b  = (const float*)d_in[4];
  const float* h1_w   = (const float*)d_in[5];
  const float* h1_b   = (const float*)d_in[6];
  const float* h2_w   = (const float*)d_in[7];
  const float* h2_b   = (const float*)d_in[8];
  const float* ln_g   = (const float*)d_in[9];
  const float* ln_b   = (const float*)d_in[10];
  const float* w1     = (const float*)d_in[11];
  const float* b1     = (const float*)d_in[12];
  const float* bn_g   = (const float*)d_in[13];
  const float* bn_b   = (const float*)d_in[14];
  const float* w2     = (const float*)d_in[15];
  const float* b2     = (const float*)d_in[16];
  const float* dec_w  = (const float*)d_in[17];
  const float* dec_b  = (const float*)d_in[18];
  float* out = (float*)d_out;

  char* ws = (char*)d_ws;
  size_t off = 0;
  auto alloc = [&](size_t bytes)->char* {
    char* p = ws + off;
    off += (bytes + 255) & ~(size_t)255;
    return p;
  };
  __half* h     = (__half*)alloc((size_t)N_*112*2);          // 14.7 MB
  char*  hnb    = alloc((size_t)N_*256);                     // 16.8 MB ([N][128] fp16)
  char*  z      = alloc((size_t)N_*448);                     // 29.4 MB ([N][224] bf16)
  unsigned* u   = (unsigned*)alloc((size_t)N_*64*4);         // 16.8 MB ([N][128] bf16)
  __hip_bfloat16* w1T = (__hip_bfloat16*)alloc((size_t)L_*224*128*2);
  __hip_bfloat16* w2T = (__hip_bfloat16*)alloc((size_t)L_*112*224*2);
  // zero-block: xs1, xs2, pooled, deg, cnt contiguous -> ONE memset
  char* zb = alloc(16*1000*4 + 16*100*4 + 16*100*4 + N_*4 + N_*4);
  float* xs1    = (float*)zb;                      // 64000 B
  float* xs2    = (float*)(zb + 64000);            //  6400 B
  float* pooled = (float*)(zb + 64000 + 6400);     //  6400 B
  int* deg      = (int*)(zb + 64000 + 6400 + 6400);
  int* cnt      = (int*)(zb + 64000 + 6400 + 6400 + N_*4);
  int* row_start  = (int*)alloc((N_+1)*4);
  int* sorted_src = (int*)alloc(E_*4);

  const int* srcs = eidx;
  const int* dsts = eidx + E_;

  hipMemsetAsync(zb, 0, 64000 + 6400 + 6400 + (size_t)N_*4*2, stream);

  {
    dim3 g1(4, 64);
    dense1_kernel<<<g1, 256, 0, stream>>>(x, h1_w, xs1);
  }
  dense2_kernel<<<16, 256, 0, stream>>>(xs1, h1_b, h2_w, xs2);

  enc_ln_kernel<<<N_/4, 256, 0, stream>>>(x, enc_w, enc_b, ln_g, ln_b, h, hnb);

  deg_kernel<<<E_/256, 256, 0, stream>>>(dsts, deg);
  scan_kernel<<<1, 1024, 0, stream>>>(deg, row_start);
  scatter_kernel<<<E_/256, 256, 0, stream>>>(srcs, dsts, row_start, cnt, sorted_src);

  prep_weights<<<(L_*224*128+255)/256, 256, 0, stream>>>(w1, w2, w1T, w2T);

  for (int i=0;i<L_;i++){
    agg_kernel<<<N_/8, 256, 0, stream>>>(hnb, row_start, sorted_src, u);
    gemm1_kernel<<<N_/64, 256, 0, stream>>>((const __hip_bfloat16*)u,
                                            w1T + (size_t)i*224*128, b1 + i*H_,
                                            bn_g + i*H_, bn_b + i*H_, z);
    if (i < L_-1) {
      gemm2_kernel<0><<<N_/64, 256, 0, stream>>>(z, w2T + (size_t)i*112*224, b2 + i*D_,
                                                 h, ln_g + (i+1)*D_, ln_b + (i+1)*D_,
                                                 hnb, pooled);
    } else {
      gemm2_kernel<1><<<N_/64, 256, 0, stream>>>(z, w2T + (size_t)i*112*224, b2 + i*D_,
                                                 h, nullptr, nullptr, hnb, pooled);
    }
  }

  final_kernel<<<1, 128, 0, stream>>>(xs2, h2_b, pooled, dec_w, dec_b, out);
}